// Round 1
// baseline (558.373 us; speedup 1.0000x reference)
//
#include <hip/hip_runtime.h>
#include <hip/hip_bf16.h>

#define T_  128
#define C_  192
#define H_  6
#define D_  32
#define C3_ 576

typedef __bf16 bf16x8 __attribute__((ext_vector_type(8)));
typedef __bf16 bf16x4 __attribute__((ext_vector_type(4)));
typedef float  f32x4  __attribute__((ext_vector_type(4)));

// Load an 8-element MFMA operand fragment: two K=16 slabs, 4 contiguous bf16 each.
__device__ __forceinline__ bf16x8 ld_frag(const __bf16* p) {
    union { bf16x8 v; struct { bf16x4 lo, hi; } s; } u;
    u.s.lo = *reinterpret_cast<const bf16x4*>(p);
    u.s.hi = *reinterpret_cast<const bf16x4*>(p + 16);
    return u.v;
}

__global__ __launch_bounds__(512) void attn_fused(
    const float* __restrict__ x,
    const float* __restrict__ w_qkv,
    const float* __restrict__ b_qkv,
    const float* __restrict__ w_proj,
    const float* __restrict__ b_proj,
    float* __restrict__ y)
{
    // LDS: strides chosen so row-stride(words) % 32 ∈ {4,20} -> <=2-way bank conflicts (free)
    __shared__ __bf16 o_s[128][200];     // attention output (bf16), 51200 B
    __shared__ __bf16 q_s[128][40];      // 10240 B
    __shared__ __bf16 k_s[128][40];      // 10240 B
    __shared__ __bf16 vt_s[32][136];     // V transposed [d][s], 8704 B
    __shared__ __bf16 pw_s[19200];       // union: P [128][136] bf16 / W-slab [96][200], 38400 B

    const int b    = blockIdx.x;
    const int tid  = threadIdx.x;
    const int wid  = tid >> 6;          // 8 waves
    const int lane = tid & 63;
    const int li   = lane & 15;
    const int g    = lane >> 4;
    const int trow = 16 * wid;          // this wave's 16-row output band

    // ---- x A-fragments for rows [trow, trow+16), K = 192 (6 ktiles), kept in regs all kernel
    bf16x8 xf[6];
    {
        const float* xr = x + ((size_t)b * T_ + trow + li) * C_;
        #pragma unroll
        for (int kt = 0; kt < 6; ++kt) {
            f32x4 a0 = *reinterpret_cast<const f32x4*>(xr + kt*32 + 4*g);
            f32x4 a1 = *reinterpret_cast<const f32x4*>(xr + kt*32 + 16 + 4*g);
            bf16x8 f;
            f[0] = (__bf16)a0[0]; f[1] = (__bf16)a0[1]; f[2] = (__bf16)a0[2]; f[3] = (__bf16)a0[3];
            f[4] = (__bf16)a1[0]; f[5] = (__bf16)a1[1]; f[6] = (__bf16)a1[2]; f[7] = (__bf16)a1[3];
            xf[kt] = f;
        }
    }

    const float scale = 0.17677669529663687f;  // 1/sqrt(32)

    for (int h = 0; h < H_; ++h) {
        __syncthreads();  // pw_s / q_s / k_s / vt_s free for reuse
        // ---- stage W_qkv slab for head h: rows n_local = sec*32+d (96), cols k (192)
        {
            const int c32 = tid & 31;
            for (int k = tid >> 5; k < C_; k += 16) {
                const float* wr = w_qkv + (size_t)k * C3_ + h * D_ + c32;
                #pragma unroll
                for (int sec = 0; sec < 3; ++sec)
                    pw_s[(sec*32 + c32) * 200 + k] = (__bf16)wr[sec * C_];
            }
        }
        __syncthreads();

        // ---- QKV GEMM: [16 x 96] = x[16 x 192] @ w[192 x 96] + bias
        #pragma unroll
        for (int nt = 0; nt < 6; ++nt) {
            const int sec  = nt >> 1;                 // 0=q 1=k 2=v
            const int dcol = (nt & 1) * 16 + li;      // 0..31 within head
            const float bias = b_qkv[sec * C_ + h * D_ + dcol];
            f32x4 acc = {bias, bias, bias, bias};
            #pragma unroll
            for (int kt = 0; kt < 6; ++kt) {
                bf16x8 bfv = ld_frag(&pw_s[(nt*16 + li) * 200 + kt*32 + 4*g]);
                acc = __builtin_amdgcn_mfma_f32_16x16x32_bf16(xf[kt], bfv, acc, 0, 0, 0);
            }
            if (sec < 2) {
                __bf16 (*dst)[40] = (sec == 0) ? q_s : k_s;
                #pragma unroll
                for (int r = 0; r < 4; ++r)
                    dst[trow + 4*g + r][dcol] = (__bf16)acc[r];
            } else {
                bf16x4 pk;
                pk[0]=(__bf16)acc[0]; pk[1]=(__bf16)acc[1]; pk[2]=(__bf16)acc[2]; pk[3]=(__bf16)acc[3];
                *reinterpret_cast<bf16x4*>(&vt_s[dcol][trow + 4*g]) = pk;  // V transposed
            }
        }
        __syncthreads();

        // ---- S = Q K^T (scaled, causal) + wave-parallel softmax
        bf16x8 qf = ld_frag(&q_s[trow + li][4*g]);
        f32x4 sacc[8];
        #pragma unroll
        for (int nt = 0; nt < 8; ++nt) {
            bf16x8 kf = ld_frag(&k_s[nt*16 + li][4*g]);
            f32x4 z = {0.f, 0.f, 0.f, 0.f};
            sacc[nt] = __builtin_amdgcn_mfma_f32_16x16x32_bf16(qf, kf, z, 0, 0, 0);
        }
        float lsum[4];
        #pragma unroll
        for (int r = 0; r < 4; ++r) {
            const int t = trow + 4*g + r;             // query index (C/D row)
            float m = -1e30f;
            #pragma unroll
            for (int nt = 0; nt < 8; ++nt) {
                const int s = nt*16 + li;             // key index (C/D col)
                float v = (s <= t) ? sacc[nt][r] * scale : -1e30f;
                sacc[nt][r] = v;
                m = fmaxf(m, v);
            }
            #pragma unroll
            for (int off = 1; off < 16; off <<= 1)
                m = fmaxf(m, __shfl_xor(m, off, 64));
            float l = 0.f;
            #pragma unroll
            for (int nt = 0; nt < 8; ++nt) {
                float p = __expf(sacc[nt][r] - m);
                sacc[nt][r] = p;
                l += p;
            }
            #pragma unroll
            for (int off = 1; off < 16; off <<= 1)
                l += __shfl_xor(l, off, 64);
            lsum[r] = l;
        }
        // write unnormalized P (bf16) into pw_s viewed as [128][136]
        #pragma unroll
        for (int nt = 0; nt < 8; ++nt) {
            #pragma unroll
            for (int r = 0; r < 4; ++r)
                pw_s[(trow + 4*g + r) * 136 + nt*16 + li] = (__bf16)sacc[nt][r];
        }
        __syncthreads();

        // ---- O = P V, then divide by row-sum; write into o_s columns [h*32, h*32+32)
        f32x4 oacc[2] = {{0.f,0.f,0.f,0.f},{0.f,0.f,0.f,0.f}};
        #pragma unroll
        for (int kk = 0; kk < 4; ++kk) {
            bf16x8 pf = ld_frag(&pw_s[(trow + li) * 136 + kk*32 + 4*g]);
            #pragma unroll
            for (int nt = 0; nt < 2; ++nt) {
                bf16x8 vf = ld_frag(&vt_s[nt*16 + li][kk*32 + 4*g]);
                oacc[nt] = __builtin_amdgcn_mfma_f32_16x16x32_bf16(pf, vf, oacc[nt], 0, 0, 0);
            }
        }
        #pragma unroll
        for (int nt = 0; nt < 2; ++nt) {
            #pragma unroll
            for (int r = 0; r < 4; ++r)
                o_s[trow + 4*g + r][h*D_ + nt*16 + li] = (__bf16)(oacc[nt][r] / lsum[r]);
        }
    }

    // ---- final projection: y = o @ w_proj + b_proj, N split in two 96-col chunks
    __syncthreads();
    bf16x8 of[6];
    #pragma unroll
    for (int kt = 0; kt < 6; ++kt)
        of[kt] = ld_frag(&o_s[trow + li][kt*32 + 4*g]);

    float* yr = y + (size_t)b * T_ * C_;
    for (int chunk = 0; chunk < 2; ++chunk) {
        __syncthreads();
        {
            const int c32 = tid & 31;
            for (int k = tid >> 5; k < C_; k += 16) {
                const float* wr = w_proj + (size_t)k * C_ + chunk * 96 + c32;
                #pragma unroll
                for (int cc = 0; cc < 3; ++cc)
                    pw_s[(cc*32 + c32) * 200 + k] = (__bf16)wr[cc * 32];
            }
        }
        __syncthreads();
        #pragma unroll
        for (int nt = 0; nt < 6; ++nt) {
            const int n = chunk * 96 + nt*16 + li;
            const float bias = b_proj[n];
            f32x4 acc = {bias, bias, bias, bias};
            #pragma unroll
            for (int kt = 0; kt < 6; ++kt) {
                bf16x8 bfv = ld_frag(&pw_s[(nt*16 + li) * 200 + kt*32 + 4*g]);
                acc = __builtin_amdgcn_mfma_f32_16x16x32_bf16(of[kt], bfv, acc, 0, 0, 0);
            }
            #pragma unroll
            for (int r = 0; r < 4; ++r)
                yr[(size_t)(trow + 4*g + r) * C_ + n] = acc[r];
        }
    }
}

extern "C" void kernel_launch(void* const* d_in, const int* in_sizes, int n_in,
                              void* d_out, int out_size, void* d_ws, size_t ws_size,
                              hipStream_t stream) {
    const float* x      = (const float*)d_in[0];
    const float* w_qkv  = (const float*)d_in[1];
    const float* b_qkv  = (const float*)d_in[2];
    const float* w_proj = (const float*)d_in[3];
    const float* b_proj = (const float*)d_in[4];
    float* y = (float*)d_out;
    const int B = in_sizes[0] / (T_ * C_);
    attn_fused<<<B, 512, 0, stream>>>(x, w_qkv, b_qkv, w_proj, b_proj, y);
}